// Round 12
// baseline (2653.196 us; speedup 1.0000x reference)
//
#include <hip/hip_runtime.h>
#include <math.h>

#define BB 256
#define TT 128
#define NN 512
#define HH 512
#define G3 1536
#define SLAB (HH * BB)     // 131072
#define XSLAB (G3 * BB)    // 393216
#define CH 16

typedef __attribute__((ext_vector_type(8))) short bf16x8;
typedef __attribute__((ext_vector_type(4))) float f32x4;
typedef unsigned short ushort;

__device__ __forceinline__ ushort bf16_rne(float f) {
    union { float f; unsigned u; } v; v.f = f;
    unsigned r = (v.u + 0x7fffu + ((v.u >> 16) & 1u)) >> 16;
    return (ushort)r;
}
__device__ __forceinline__ float bf16_tof(ushort h) {
    union { float f; unsigned u; } v; v.u = ((unsigned)h) << 16;
    return v.f;
}
__device__ __forceinline__ float sigm(float v) { return 1.f / (1.f + expf(-v)); }

__device__ __forceinline__ void split8(float4 a, float4 b, uint4& hi, uint4& lo) {
    float f[8] = {a.x, a.y, a.z, a.w, b.x, b.y, b.z, b.w};
    ushort hs[8], ls[8];
#pragma unroll
    for (int q = 0; q < 8; ++q) {
        ushort h = bf16_rne(f[q]);
        hs[q] = h;
        ls[q] = bf16_rne(f[q] - bf16_tof(h));
    }
    hi = *(uint4*)hs;
    lo = *(uint4*)ls;
}

// zero the four H-state slot-1 slabs (4 x 131072 ushorts)
__global__ __launch_bounds__(256) void zero4(
    ushort* a, ushort* b, ushort* c, ushort* d) {
    int i = blockIdx.x * 256 + threadIdx.x;     // grid 256
    int sel = i >> 14, r = i & 16383;
    uint4 z = {0u, 0u, 0u, 0u};
    ushort* p = (sel == 0) ? a : (sel == 1) ? b : (sel == 2) ? c : d;
    ((uint4*)p)[r] = z;
}

__global__ __launch_bounds__(256) void convert_split(
    const float* __restrict__ in, ushort* __restrict__ hi,
    ushort* __restrict__ lo, int n) {
    int i = (blockIdx.x * 256 + threadIdx.x) * 4;
    if (i >= n) return;
    float4 v = *(const float4*)(in + i);
    float f[4] = {v.x, v.y, v.z, v.w};
    ushort h[4], l[4];
#pragma unroll
    for (int q = 0; q < 4; ++q) {
        ushort hh = bf16_rne(f[q]);
        h[q] = hh;
        l[q] = bf16_rne(f[q] - bf16_tof(hh));
    }
    *(ushort4*)(hi + i) = *(ushort4*)h;
    *(ushort4*)(lo + i) = *(ushort4*)l;
}

// One-time: pack Whh0/Wih1/Whh1 into per-lane MFMA fragment order (r10/r11, proven).
__global__ __launch_bounds__(64) void pack_swz(
    const float* __restrict__ Whh0, const float* __restrict__ Wih1,
    const float* __restrict__ Whh1, ushort* __restrict__ pk) {
    const int bi = blockIdx.x;                 // (((sec*32+p)*4+kq)*4+it)
    const int it = bi & 3, kq = (bi >> 2) & 3, p = (bi >> 4) & 31, sec = bi >> 9;
    const float* W = (sec == 0) ? Whh0 : (sec == 1) ? Wih1 : Whh1;
    const int lane = threadIdx.x;
    const int l15 = lane & 15, l4 = lane >> 4;
    ushort* base = pk + (size_t)bi * 3072 + lane * 8;
#pragma unroll
    for (int g = 0; g < 3; ++g) {
        int grow = g * 512 + p * 16 + l15;
        const float* src = W + (size_t)grow * 512 + kq * 128 + it * 32 + l4 * 8;
        ushort hs[8], ls[8];
#pragma unroll
        for (int e = 0; e < 8; ++e) {
            float v = src[e];
            ushort h = bf16_rne(v);
            hs[e] = h;
            ls[e] = bf16_rne(v - bf16_tof(h));
        }
        *(uint4*)(base + g * 1024) = *(uint4*)hs;
        *(uint4*)(base + g * 1024 + 512) = *(uint4*)ls;
    }
}

// xi0 prologue chunk GEMM (r7-r11, proven) — used once for t=0..7
__global__ __launch_bounds__(256) void xi_mfma_x(
    const ushort* __restrict__ Wh, const ushort* __restrict__ Wl,
    const float* __restrict__ x, int t0,
    const float* __restrict__ bias, float* __restrict__ out) {
    __shared__ ushort As[2][128][40];
    __shared__ ushort Bs[2][128][40];
    const int tid = threadIdx.x;
    const int n0 = blockIdx.x * 128;
    const int g0 = blockIdx.y * 128;
    const int tl = n0 >> 8, b0 = n0 & 255;
    const int tg = t0 + tl;
    const int w = tid >> 6, lane = tid & 63;
    const int wg = (w >> 1) * 64, wb = (w & 1) * 64;
    const int l15 = lane & 15, l4 = lane >> 4;
    const int sr = tid >> 2, sc = (tid & 3) * 8;

    f32x4 acc[4][4] = {};
    for (int kc = 0; kc < 512; kc += 32) {
        uint4 a0 = *(const uint4*)(Wh + (size_t)(g0 + sr) * 512 + kc + sc);
        uint4 a1 = *(const uint4*)(Wh + (size_t)(g0 + 64 + sr) * 512 + kc + sc);
        uint4 a2 = *(const uint4*)(Wl + (size_t)(g0 + sr) * 512 + kc + sc);
        uint4 a3 = *(const uint4*)(Wl + (size_t)(g0 + 64 + sr) * 512 + kc + sc);
        const float* xr0 = x + ((size_t)(b0 + sr) * TT + tg) * NN + kc + sc;
        const float* xr1 = x + ((size_t)(b0 + 64 + sr) * TT + tg) * NN + kc + sc;
        float4 f00 = *(const float4*)xr0, f01 = *(const float4*)(xr0 + 4);
        float4 f10 = *(const float4*)xr1, f11 = *(const float4*)(xr1 + 4);
        uint4 h0v, l0v, h1v, l1v;
        split8(f00, f01, h0v, l0v);
        split8(f10, f11, h1v, l1v);
        __syncthreads();
        *(uint4*)&As[0][sr][sc] = a0;      *(uint4*)&As[0][64 + sr][sc] = a1;
        *(uint4*)&As[1][sr][sc] = a2;      *(uint4*)&As[1][64 + sr][sc] = a3;
        *(uint4*)&Bs[0][sr][sc] = h0v;     *(uint4*)&Bs[0][64 + sr][sc] = h1v;
        *(uint4*)&Bs[1][sr][sc] = l0v;     *(uint4*)&Bs[1][64 + sr][sc] = l1v;
        __syncthreads();
        bf16x8 ah[4], al[4], bh[4], bl[4];
#pragma unroll
        for (int i = 0; i < 4; ++i) {
            ah[i] = *(const bf16x8*)&As[0][wg + 16 * i + l15][l4 * 8];
            al[i] = *(const bf16x8*)&As[1][wg + 16 * i + l15][l4 * 8];
            bh[i] = *(const bf16x8*)&Bs[0][wb + 16 * i + l15][l4 * 8];
            bl[i] = *(const bf16x8*)&Bs[1][wb + 16 * i + l15][l4 * 8];
        }
#pragma unroll
        for (int i = 0; i < 4; ++i)
#pragma unroll
            for (int j = 0; j < 4; ++j) {
                acc[i][j] = __builtin_amdgcn_mfma_f32_16x16x32_bf16(ah[i], bh[j], acc[i][j], 0, 0, 0);
                acc[i][j] = __builtin_amdgcn_mfma_f32_16x16x32_bf16(ah[i], bl[j], acc[i][j], 0, 0, 0);
                acc[i][j] = __builtin_amdgcn_mfma_f32_16x16x32_bf16(al[i], bh[j], acc[i][j], 0, 0, 0);
            }
    }
    float* op = out + (size_t)tl * XSLAB;
#pragma unroll
    for (int i = 0; i < 4; ++i) {
        int gbase = g0 + wg + 16 * i + l4 * 4;
#pragma unroll
        for (int r = 0; r < 4; ++r) {
            float bv = bias[gbase + r];
#pragma unroll
            for (int j = 0; j < 4; ++j)
                op[(size_t)(gbase + r) * 256 + b0 + wb + 16 * j + l15] = acc[i][j][r] + bv;
        }
    }
}

// cross-k-quarter reduction via LDS (r9-r11, validated)
template <int NG>
__device__ __forceinline__ void kreduceN(float* scr, int kq, int ct, int l15, int l4,
                                         f32x4* acc) {
    const int SS = NG * 272;
    const int slot = (kq >> 1) * 2 + ct;
    const int pos0 = (l4 * 4) * 17 + l15;
    __syncthreads();
    if (kq & 1) {
#pragma unroll
        for (int g = 0; g < NG; ++g)
#pragma unroll
            for (int q = 0; q < 4; ++q)
                scr[slot * SS + g * 272 + pos0 + q * 17] = acc[g][q];
    }
    __syncthreads();
    if (!(kq & 1)) {
#pragma unroll
        for (int g = 0; g < NG; ++g)
#pragma unroll
            for (int q = 0; q < 4; ++q)
                acc[g][q] += scr[slot * SS + g * 272 + pos0 + q * 17];
    }
    if (kq == 2) {
#pragma unroll
        for (int g = 0; g < NG; ++g)
#pragma unroll
            for (int q = 0; q < 4; ++q)
                scr[(2 + ct) * SS + g * 272 + pos0 + q * 17] = acc[g][q];
    }
    __syncthreads();
    if (kq == 0) {
#pragma unroll
        for (int g = 0; g < NG; ++g)
#pragma unroll
            for (int q = 0; q < 4; ++q)
                acc[g][q] += scr[(2 + ct) * SS + g * 272 + pos0 + q * 17];
    }
}

// Per-step kernel: 3 sections x 256 blocks, 512 thr.
//  sec0  (bi<256):    L0(t=s): gh0 = Whh0 x H0[t-1]; gates -> H0[t] pair
//  rec1f (256..511):  layer-1 t=s-1: xi1 = Wih1 x H0[t] AND gh1 = Whh1 x H1[t-1];
//                     full GRU epilogue -> H1[t] pair
//  XIC   (512..767):  xi0 for t=s+8 into ring slot (s+8)&15  [r9's xi0 phase]
__global__ __launch_bounds__(512) void step_v12(
    int s, const ushort* __restrict__ pk,
    const float* __restrict__ x,
    const ushort* __restrict__ W0h, const ushort* __restrict__ W0l,
    float* __restrict__ xi0,
    const float* __restrict__ bih0, const float* __restrict__ bih1,
    const float* __restrict__ bhh0, const float* __restrict__ bhh1,
    ushort* __restrict__ H0h, ushort* __restrict__ H0l,
    ushort* __restrict__ H1h, ushort* __restrict__ H1l) {
    __shared__ float scr[6528];
    const int bi = blockIdx.x;
    const int sec = bi >> 8, local = bi & 255;
    const int p = (local & 7) * 4 + ((local >> 3) & 3);   // panel, XCD-exclusive
    const int b0 = (local >> 5) * 32;
    const int tid = threadIdx.x, w = tid >> 6, lane = tid & 63;
    const int l15 = lane & 15, l4 = lane >> 4;
    const int kq = w >> 1, ct = w & 1;
    const int brow = b0 + ct * 16 + l15;

    if (sec == 0) {
        const int t = s;
        if (t > 127) return;
        const int sl = (t - 1) & 1;
        const ushort* Bh = H0h + (size_t)sl * SLAB;
        const ushort* Bl = H0l + (size_t)sl * SLAB;
        const ushort* baseA = pk + (size_t)((0 * 32 + p) * 4 + kq) * 12288 + lane * 8;
        const ushort* bhp = Bh + (size_t)brow * 512 + kq * 128 + l4 * 8;
        const ushort* blp = Bl + (size_t)brow * 512 + kq * 128 + l4 * 8;
        f32x4 acc[3] = {};
#pragma unroll
        for (int it = 0; it < 4; ++it) {
            bf16x8 bh = *(const bf16x8*)(bhp + it * 32);
            bf16x8 bl = *(const bf16x8*)(blp + it * 32);
#pragma unroll
            for (int g = 0; g < 3; ++g) {
                const ushort* rec = baseA + (it * 3 + g) * 1024;
                bf16x8 ah = *(const bf16x8*)rec;
                bf16x8 al = *(const bf16x8*)(rec + 512);
                acc[g] = __builtin_amdgcn_mfma_f32_16x16x32_bf16(ah, bh, acc[g], 0, 0, 0);
                acc[g] = __builtin_amdgcn_mfma_f32_16x16x32_bf16(ah, bl, acc[g], 0, 0, 0);
                acc[g] = __builtin_amdgcn_mfma_f32_16x16x32_bf16(al, bh, acc[g], 0, 0, 0);
            }
        }
        kreduceN<3>(scr, kq, ct, l15, l4, acc);
        if (kq == 0) {
            const float* xi = xi0 + (size_t)(t & (CH - 1)) * XSLAB;
            const ushort* Hph = H0h + (size_t)sl * SLAB;
            const ushort* Hpl = H0l + (size_t)sl * SLAB;
            ushort* Hh = H0h + (size_t)(t & 1) * SLAB;
            ushort* Hl = H0l + (size_t)(t & 1) * SLAB;
            const int b = brow;
            size_t o = (size_t)b * 512 + p * 16 + l4 * 4;
            ushort4 hph = *(const ushort4*)(Hph + o);
            ushort4 hpl = *(const ushort4*)(Hpl + o);
            const ushort* hph_ = (const ushort*)&hph;
            const ushort* hpl_ = (const ushort*)&hpl;
            ushort hq[4], lq[4];
#pragma unroll
            for (int q = 0; q < 4; ++q) {
                int jrow = p * 16 + l4 * 4 + q;
                float xr = xi[(size_t)jrow * 256 + b];
                float xz = xi[(size_t)(512 + jrow) * 256 + b];
                float xn = xi[(size_t)(1024 + jrow) * 256 + b];
                float hp = bf16_tof(hph_[q]) + bf16_tof(hpl_[q]);
                float rr = sigm(xr + acc[0][q] + bhh0[jrow]);
                float zz = sigm(xz + acc[1][q] + bhh0[512 + jrow]);
                float nn = tanhf(xn + rr * (acc[2][q] + bhh0[1024 + jrow]));
                float hv = (1.f - zz) * nn + zz * hp;
                ushort hh = bf16_rne(hv);
                hq[q] = hh;
                lq[q] = bf16_rne(hv - bf16_tof(hh));
            }
            *(ushort4*)(Hh + o) = *(ushort4*)hq;
            *(ushort4*)(Hl + o) = *(ushort4*)lq;
        }
    } else if (sec == 1) {
        const int t = s - 1;
        if (t < 0 || t > 127) return;
        const int slX = t & 1, slG = (t - 1) & 1;
        const ushort* BhX = H0h + (size_t)slX * SLAB;
        const ushort* BlX = H0l + (size_t)slX * SLAB;
        const ushort* BhG = H1h + (size_t)slG * SLAB;
        const ushort* BlG = H1l + (size_t)slG * SLAB;
        const ushort* baseAX = pk + (size_t)((1 * 32 + p) * 4 + kq) * 12288 + lane * 8;
        const ushort* baseAG = pk + (size_t)((2 * 32 + p) * 4 + kq) * 12288 + lane * 8;
        const ushort* bhpX = BhX + (size_t)brow * 512 + kq * 128 + l4 * 8;
        const ushort* blpX = BlX + (size_t)brow * 512 + kq * 128 + l4 * 8;
        const ushort* bhpG = BhG + (size_t)brow * 512 + kq * 128 + l4 * 8;
        const ushort* blpG = BlG + (size_t)brow * 512 + kq * 128 + l4 * 8;
        f32x4 acc[6] = {};
#pragma unroll
        for (int it = 0; it < 4; ++it) {
            bf16x8 bhX = *(const bf16x8*)(bhpX + it * 32);
            bf16x8 blX = *(const bf16x8*)(blpX + it * 32);
            bf16x8 bhG = *(const bf16x8*)(bhpG + it * 32);
            bf16x8 blG = *(const bf16x8*)(blpG + it * 32);
#pragma unroll
            for (int g = 0; g < 3; ++g) {
                const ushort* recX = baseAX + (it * 3 + g) * 1024;
                const ushort* recG = baseAG + (it * 3 + g) * 1024;
                bf16x8 ahX = *(const bf16x8*)recX;
                bf16x8 alX = *(const bf16x8*)(recX + 512);
                bf16x8 ahG = *(const bf16x8*)recG;
                bf16x8 alG = *(const bf16x8*)(recG + 512);
                acc[g] = __builtin_amdgcn_mfma_f32_16x16x32_bf16(ahX, bhX, acc[g], 0, 0, 0);
                acc[g] = __builtin_amdgcn_mfma_f32_16x16x32_bf16(ahX, blX, acc[g], 0, 0, 0);
                acc[g] = __builtin_amdgcn_mfma_f32_16x16x32_bf16(alX, bhX, acc[g], 0, 0, 0);
                acc[3 + g] = __builtin_amdgcn_mfma_f32_16x16x32_bf16(ahG, bhG, acc[3 + g], 0, 0, 0);
                acc[3 + g] = __builtin_amdgcn_mfma_f32_16x16x32_bf16(ahG, blG, acc[3 + g], 0, 0, 0);
                acc[3 + g] = __builtin_amdgcn_mfma_f32_16x16x32_bf16(alG, bhG, acc[3 + g], 0, 0, 0);
            }
        }
        kreduceN<6>(scr, kq, ct, l15, l4, acc);
        if (kq == 0) {
            const int slp = (t - 1) & 1;
            const ushort* Hph = H1h + (size_t)slp * SLAB;
            const ushort* Hpl = H1l + (size_t)slp * SLAB;
            ushort* Hh = H1h + (size_t)(t & 1) * SLAB;
            ushort* Hl = H1l + (size_t)(t & 1) * SLAB;
            const int b = brow;
            size_t o = (size_t)b * 512 + p * 16 + l4 * 4;
            ushort4 hph = *(const ushort4*)(Hph + o);
            ushort4 hpl = *(const ushort4*)(Hpl + o);
            const ushort* hph_ = (const ushort*)&hph;
            const ushort* hpl_ = (const ushort*)&hpl;
            ushort hq[4], lq[4];
#pragma unroll
            for (int q = 0; q < 4; ++q) {
                int jrow = p * 16 + l4 * 4 + q;
                float xr = acc[0][q] + bih1[jrow];
                float xz = acc[1][q] + bih1[512 + jrow];
                float xn = acc[2][q] + bih1[1024 + jrow];
                float hp = bf16_tof(hph_[q]) + bf16_tof(hpl_[q]);
                float rr = sigm(xr + acc[3][q] + bhh1[jrow]);
                float zz = sigm(xz + acc[4][q] + bhh1[512 + jrow]);
                float nn = tanhf(xn + rr * (acc[5][q] + bhh1[1024 + jrow]));
                float hv = (1.f - zz) * nn + zz * hp;
                ushort hh = bf16_rne(hv);
                hq[q] = hh;
                lq[q] = bf16_rne(hv - bf16_tof(hh));
            }
            *(ushort4*)(Hh + o) = *(ushort4*)hq;
            *(ushort4*)(Hl + o) = *(ushort4*)lq;
        }
    } else {
        // XIC: xi0[t=s+8] = W0ih x x[:,t,:] + bih0 (r9's xi0 phase, 1 timestep)
        const int tt = s + 8;
        if (tt > 127) return;
        const float* xb = x + ((size_t)brow * TT + tt) * NN;
        f32x4 acc[3] = {};
#pragma unroll
        for (int it = 0; it < 4; ++it) {
            const int k = kq * 128 + it * 32 + l4 * 8;
            float4 f0 = *(const float4*)(xb + k);
            float4 f1 = *(const float4*)(xb + k + 4);
            uint4 bhv, blv;
            split8(f0, f1, bhv, blv);
            bf16x8 bh = *(bf16x8*)&bhv, bl = *(bf16x8*)&blv;
#pragma unroll
            for (int g = 0; g < 3; ++g) {
                int grow = g * 512 + p * 16 + l15;
                bf16x8 ah = *(const bf16x8*)(W0h + (size_t)grow * 512 + k);
                bf16x8 al = *(const bf16x8*)(W0l + (size_t)grow * 512 + k);
                acc[g] = __builtin_amdgcn_mfma_f32_16x16x32_bf16(ah, bh, acc[g], 0, 0, 0);
                acc[g] = __builtin_amdgcn_mfma_f32_16x16x32_bf16(ah, bl, acc[g], 0, 0, 0);
                acc[g] = __builtin_amdgcn_mfma_f32_16x16x32_bf16(al, bh, acc[g], 0, 0, 0);
            }
        }
        kreduceN<3>(scr, kq, ct, l15, l4, acc);
        if (kq == 0) {
            float* xo = xi0 + (size_t)(tt & (CH - 1)) * XSLAB;
            const int b = brow;
#pragma unroll
            for (int g = 0; g < 3; ++g)
#pragma unroll
                for (int q = 0; q < 4; ++q) {
                    int grow = g * 512 + p * 16 + l4 * 4 + q;
                    xo[(size_t)grow * 256 + b] = acc[g][q] + bih0[grow];
                }
        }
    }
}

// ---- tail ------------------------------------------------------------------

__device__ __forceinline__ float blockReduceSum(float v, float* tmp) {
    __syncthreads();
#pragma unroll
    for (int o = 32; o; o >>= 1) v += __shfl_down(v, o);
    if ((threadIdx.x & 63) == 0) tmp[threadIdx.x >> 6] = v;
    __syncthreads();
    if (threadIdx.x == 0) tmp[4] = tmp[0] + tmp[1] + tmp[2] + tmp[3];
    __syncthreads();
    return tmp[4];
}

__device__ __forceinline__ float blockReduceMax(float v, float* tmp) {
    __syncthreads();
#pragma unroll
    for (int o = 32; o; o >>= 1) v = fmaxf(v, __shfl_down(v, o));
    if ((threadIdx.x & 63) == 0) tmp[threadIdx.x >> 6] = v;
    __syncthreads();
    if (threadIdx.x == 0) tmp[4] = fmaxf(fmaxf(tmp[0], tmp[1]), fmaxf(tmp[2], tmp[3]));
    __syncthreads();
    return tmp[4];
}

// head: reads final h1 directly from the H1 hi/lo pair slabs (b-major)
__global__ __launch_bounds__(256) void head_kernel(
    const ushort* __restrict__ H1hs, const ushort* __restrict__ H1ls,
    const float* __restrict__ fcw, const float* __restrict__ fcb,
    float* __restrict__ out) {
    __shared__ __align__(16) float hrow[512];
    __shared__ float wv[512];
    __shared__ float ov[512];
    __shared__ float tmp[8];
    const int b = blockIdx.x, tid = threadIdx.x;
    {
        size_t o = (size_t)b * 512 + tid;
        hrow[tid]       = bf16_tof(H1hs[o]) + bf16_tof(H1ls[o]);
        hrow[tid + 256] = bf16_tof(H1hs[o + 256]) + bf16_tof(H1ls[o + 256]);
    }
    __syncthreads();

    float s[2];
#pragma unroll
    for (int q = 0; q < 2; ++q) {
        int n = tid + q * 256;
        const float* wr = fcw + (size_t)n * 512;
        float acc = 0.f;
        for (int k = 0; k < 512; k += 4) {
            float4 wq = *(const float4*)(wr + k);
            acc += wq.x * hrow[k] + wq.y * hrow[k + 1] + wq.z * hrow[k + 2] + wq.w * hrow[k + 3];
        }
        float l = acc + fcb[n];
        s[q] = l / (1.f + expf(-l));
    }

    float mx = blockReduceMax(fmaxf(s[0], s[1]), tmp);
    float e0 = expf(s[0] - mx), e1 = expf(s[1] - mx);
    float sum = blockReduceSum(e0 + e1, tmp);
    float w0 = e0 / sum, w1 = e1 / sum;

    ov[tid] = w0;       ov[tid + 256] = w1;
    wv[tid]       = fminf(fmaxf(w0, 0.f), 0.1f);
    wv[tid + 256] = fminf(fmaxf(w1, 0.f), 0.1f);
    __syncthreads();

    for (int it = 0; it < 32; ++it) {
        float wc0 = wv[tid], wc1 = wv[tid + 256];
        float o0 = ov[tid], o1 = ov[tid + 256];
        float leftover = blockReduceSum((o0 - wc0) + (o1 - wc1), tmp);
        float n0 = (wc0 != 0.1f) ? wc0 : 0.f;
        float n1 = (wc1 != 0.1f) ? wc1 : 0.f;
        float denom = blockReduceSum(n0 + n1, tmp);
        float w20 = wc0 + leftover * n0 / denom;
        float w21 = wc1 + leftover * n1 / denom;
        float fl = ((w20 > 0.1f) || (w21 > 0.1f)) ? 1.f : 0.f;
        bool again = blockReduceSum(fl, tmp) > 0.f;
        __syncthreads();
        ov[tid] = w20; ov[tid + 256] = w21;
        wv[tid]       = again ? fminf(fmaxf(w20, 0.f), 0.1f) : w20;
        wv[tid + 256] = again ? fminf(fmaxf(w21, 0.f), 0.1f) : w21;
        __syncthreads();
        if (!again) break;
    }

    out[(size_t)b * 512 + tid]       = wv[tid];
    out[(size_t)b * 512 + 256 + tid] = wv[tid + 256];
}

extern "C" void kernel_launch(void* const* d_in, const int* in_sizes, int n_in,
                              void* d_out, int out_size, void* d_ws, size_t ws_size,
                              hipStream_t stream) {
    const float* x    = (const float*)d_in[0];
    const float* Wih0 = (const float*)d_in[1];
    const float* Whh0 = (const float*)d_in[2];
    const float* bih0 = (const float*)d_in[3];
    const float* bhh0 = (const float*)d_in[4];
    const float* Wih1 = (const float*)d_in[5];
    const float* Whh1 = (const float*)d_in[6];
    const float* bih1 = (const float*)d_in[7];
    const float* bhh1 = (const float*)d_in[8];
    const float* fcw  = (const float*)d_in[9];
    const float* fcb  = (const float*)d_in[10];
    float* out = (float*)d_out;

    const size_t WHALF = (size_t)G3 * HH;               // 786432
    ushort* W0h = (ushort*)d_ws;
    ushort* W0l = W0h + WHALF;
    ushort* pk  = W0l + WHALF;                          // 1536*3072 ushorts
    float* xi0 = (float*)(pk + (size_t)1536 * 3072);    // [CH][XSLAB] ring
    ushort* H0h = (ushort*)(xi0 + (size_t)CH * XSLAB);  // [2][SLAB] each
    ushort* H0l = H0h + 2 * (size_t)SLAB;
    ushort* H1h = H0l + 2 * (size_t)SLAB;
    ushort* H1l = H1h + 2 * (size_t)SLAB;

    convert_split<<<(G3 * HH) / 1024, 256, 0, stream>>>(Wih0, W0h, W0l, G3 * HH);
    pack_swz<<<1536, 64, 0, stream>>>(Whh0, Wih1, Whh1, pk);
    zero4<<<256, 256, 0, stream>>>(H0h + SLAB, H0l + SLAB, H1h + SLAB, H1l + SLAB);
    // prologue xi0 for t = 0..7
    xi_mfma_x<<<dim3(16, 12), 256, 0, stream>>>(W0h, W0l, x, 0, bih0, xi0);

    for (int s = 0; s <= 128; ++s)
        step_v12<<<768, 512, 0, stream>>>(s, pk, x, W0h, W0l, xi0,
                                          bih0, bih1, bhh0, bhh1,
                                          H0h, H0l, H1h, H1l);

    head_kernel<<<BB, 256, 0, stream>>>(H1h + SLAB, H1l + SLAB, fcw, fcb, out);
}

// Round 13
// 2099.912 us; speedup vs baseline: 1.2635x; 1.2635x over previous
//
#include <hip/hip_runtime.h>
#include <math.h>

#define BB 256
#define TT 128
#define NN 512
#define HH 512
#define G3 1536
#define SLAB (HH * BB)     // 131072
#define XSLAB (G3 * BB)    // 393216
#define CH 16              // timesteps per xi0 chunk

typedef __attribute__((ext_vector_type(8))) short bf16x8;
typedef __attribute__((ext_vector_type(4))) float f32x4;

__device__ __forceinline__ unsigned short bf16_rne(float f) {
    union { float f; unsigned int u; } v; v.f = f;
    unsigned int r = (v.u + 0x7fffu + ((v.u >> 16) & 1u)) >> 16;
    return (unsigned short)r;
}
__device__ __forceinline__ float bf16_tof(unsigned short h) {
    union { float f; unsigned int u; } v; v.u = ((unsigned int)h) << 16;
    return v.f;
}
__device__ __forceinline__ float sigm(float v) { return 1.f / (1.f + expf(-v)); }

__global__ void zero_kernel(float* p, int n) {
    int i = blockIdx.x * blockDim.x + threadIdx.x;
    if (i < n) p[i] = 0.f;
}

// fp32 -> hi/lo bf16 split (row-major, for xi_mfma_x's W0ih)
__global__ __launch_bounds__(256) void convert_split(
    const float* __restrict__ in, unsigned short* __restrict__ hi,
    unsigned short* __restrict__ lo, int n) {
    int i = (blockIdx.x * 256 + threadIdx.x) * 4;
    if (i >= n) return;
    float4 v = *(const float4*)(in + i);
    float f[4] = {v.x, v.y, v.z, v.w};
    ushort4 h, l;
    unsigned short* hp = (unsigned short*)&h;
    unsigned short* lp = (unsigned short*)&l;
#pragma unroll
    for (int q = 0; q < 4; ++q) {
        unsigned short hh = bf16_rne(f[q]);
        hp[q] = hh;
        lp[q] = bf16_rne(f[q] - bf16_tof(hh));
    }
    *(ushort4*)(hi + i) = h;
    *(ushort4*)(lo + i) = l;
}

// One-time: pack Whh0/Wih1/Whh1 into split-bf16 staged tiles.
// tile (set,p,kc): [hi 48rows x 40k | lo 48x40 | pad] = 4096 ushorts (8192 B).
// rows = 3 gates x 16 j (j = p*16 + row&15, gate = row>>4).
__global__ __launch_bounds__(128) void pack_rec(
    const float* __restrict__ Whh0, const float* __restrict__ Wih1,
    const float* __restrict__ Whh1, unsigned short* __restrict__ pk) {
    int bi = blockIdx.x;                 // 0..1535 = set*512 + p*16 + kc
    int set = bi >> 9, rem = bi & 511;
    int p = rem >> 4, kc = rem & 15;
    const float* W = (set == 0) ? Whh0 : (set == 1) ? Wih1 : Whh1;
    unsigned short* tp = pk + (size_t)bi * 4096;
    int tid = threadIdx.x;
#pragma unroll
    for (int i = 0; i < 12; ++i) {
        int idx = tid * 12 + i;          // 0..1535
        int row = idx >> 5, k = idx & 31;
        int grow = (row >> 4) * 512 + p * 16 + (row & 15);
        float v = W[(size_t)grow * 512 + kc * 32 + k];
        unsigned short h = bf16_rne(v);
        tp[row * 40 + k] = h;
        tp[1920 + row * 40 + k] = bf16_rne(v - bf16_tof(h));
    }
    if (tid < 32)
#pragma unroll
        for (int i = 0; i < 8; ++i) tp[3840 + tid * 8 + i] = 0;
}

// xi0 chunk GEMM (r7, proven): out[tl][g][b] = W0ih x x[:, t0+tl, :] + bih0
__global__ __launch_bounds__(256) void xi_mfma_x(
    const unsigned short* __restrict__ Wh, const unsigned short* __restrict__ Wl,
    const float* __restrict__ x, int t0,
    const float* __restrict__ bias, float* __restrict__ out) {
    __shared__ unsigned short As[2][128][40];
    __shared__ unsigned short Bs[2][128][40];
    const int tid = threadIdx.x;
    const int n0 = blockIdx.x * 128;
    const int g0 = blockIdx.y * 128;
    const int tl = n0 >> 8, b0 = n0 & 255;
    const int tg = t0 + tl;
    const int w = tid >> 6, lane = tid & 63;
    const int wg = (w >> 1) * 64, wb = (w & 1) * 64;
    const int l15 = lane & 15, l4 = lane >> 4;
    const int sr = tid >> 2, sc = (tid & 3) * 8;

    f32x4 acc[4][4] = {};
    for (int kc = 0; kc < 512; kc += 32) {
        uint4 a0 = *(const uint4*)(Wh + (size_t)(g0 + sr) * 512 + kc + sc);
        uint4 a1 = *(const uint4*)(Wh + (size_t)(g0 + 64 + sr) * 512 + kc + sc);
        uint4 a2 = *(const uint4*)(Wl + (size_t)(g0 + sr) * 512 + kc + sc);
        uint4 a3 = *(const uint4*)(Wl + (size_t)(g0 + 64 + sr) * 512 + kc + sc);
        const float* xr0 = x + ((size_t)(b0 + sr) * TT + tg) * NN + kc + sc;
        const float* xr1 = x + ((size_t)(b0 + 64 + sr) * TT + tg) * NN + kc + sc;
        float4 f00 = *(const float4*)xr0, f01 = *(const float4*)(xr0 + 4);
        float4 f10 = *(const float4*)xr1, f11 = *(const float4*)(xr1 + 4);
        float fa[8] = {f00.x, f00.y, f00.z, f00.w, f01.x, f01.y, f01.z, f01.w};
        float fb[8] = {f10.x, f10.y, f10.z, f10.w, f11.x, f11.y, f11.z, f11.w};
        unsigned short h0v[8], l0v[8], h1v[8], l1v[8];
#pragma unroll
        for (int q = 0; q < 8; ++q) {
            unsigned short hh = bf16_rne(fa[q]);
            h0v[q] = hh; l0v[q] = bf16_rne(fa[q] - bf16_tof(hh));
            hh = bf16_rne(fb[q]);
            h1v[q] = hh; l1v[q] = bf16_rne(fb[q] - bf16_tof(hh));
        }
        __syncthreads();
        *(uint4*)&As[0][sr][sc] = a0;      *(uint4*)&As[0][64 + sr][sc] = a1;
        *(uint4*)&As[1][sr][sc] = a2;      *(uint4*)&As[1][64 + sr][sc] = a3;
        *(uint4*)&Bs[0][sr][sc] = *(uint4*)h0v;  *(uint4*)&Bs[0][64 + sr][sc] = *(uint4*)h1v;
        *(uint4*)&Bs[1][sr][sc] = *(uint4*)l0v;  *(uint4*)&Bs[1][64 + sr][sc] = *(uint4*)l1v;
        __syncthreads();
        bf16x8 ah[4], al[4], bh[4], bl[4];
#pragma unroll
        for (int i = 0; i < 4; ++i) {
            ah[i] = *(const bf16x8*)&As[0][wg + 16 * i + l15][l4 * 8];
            al[i] = *(const bf16x8*)&As[1][wg + 16 * i + l15][l4 * 8];
            bh[i] = *(const bf16x8*)&Bs[0][wb + 16 * i + l15][l4 * 8];
            bl[i] = *(const bf16x8*)&Bs[1][wb + 16 * i + l15][l4 * 8];
        }
#pragma unroll
        for (int i = 0; i < 4; ++i)
#pragma unroll
            for (int j = 0; j < 4; ++j) {
                acc[i][j] = __builtin_amdgcn_mfma_f32_16x16x32_bf16(ah[i], bh[j], acc[i][j], 0, 0, 0);
                acc[i][j] = __builtin_amdgcn_mfma_f32_16x16x32_bf16(ah[i], bl[j], acc[i][j], 0, 0, 0);
                acc[i][j] = __builtin_amdgcn_mfma_f32_16x16x32_bf16(al[i], bh[j], acc[i][j], 0, 0, 0);
            }
    }
    float* op = out + (size_t)tl * XSLAB;
#pragma unroll
    for (int i = 0; i < 4; ++i) {
        int gbase = g0 + wg + 16 * i + l4 * 4;
#pragma unroll
        for (int r = 0; r < 4; ++r) {
            float bv = bias[gbase + r];
#pragma unroll
            for (int j = 0; j < 4; ++j)
                op[(size_t)(gbase + r) * 256 + b0 + wb + 16 * j + l15] = acc[i][j][r] + bv;
        }
    }
}

// Per-step kernel: 3 sections x 256 blocks.
//  sec0 L0(t=s):  gh0 = Whh0 x h0[t-1]bf, gates -> h0[t] (+ bf16 b-major)
//  sec1 XI1(t=s-1): xi1 = Wih1 x h0[t]bf + bih1 -> xi1 slab
//  sec2 L1(t=s-2): gh1 = Whh1 x h1[t-1]bf, gates(xi1) -> h1[t] (+ bf16)
// block: 48rows x 32b tile; 4 waves = 2 bcol x 2 k-groups; reg-staged dbuf LDS.
__global__ __launch_bounds__(256) void step_mfma(
    int s, const unsigned short* __restrict__ pk,
    const float* __restrict__ xi0, float* __restrict__ xi1,
    const float* __restrict__ bih1,
    const float* __restrict__ bhh0, const float* __restrict__ bhh1,
    float* __restrict__ h0f, float* __restrict__ h1f,
    unsigned short* __restrict__ H0h, unsigned short* __restrict__ H0l,
    unsigned short* __restrict__ H1h, unsigned short* __restrict__ H1l) {
    __shared__ __align__(16) unsigned short lds[16384];  // 4 bufs x 4096 ushorts
    __shared__ float hs[16][33];
    const int bi = blockIdx.x;
    const int sec = bi >> 8;
    const int local = bi & 255;
    const int t = (sec == 0) ? s : (sec == 1) ? s - 1 : s - 2;
    if (t < 0 || t > 127) return;
    const int p = (local & 7) * 4 + ((local >> 3) & 3);   // XCD-grouped panels
    const int bt = local >> 5;
    const int b0 = bt * 32;
    const int tid = threadIdx.x, w = tid >> 6, lane = tid & 63;
    const int l15 = lane & 15, l4 = lane >> 4;
    const int kk = w >> 1, bcol = w & 1;
    const int lt = tid & 127;

    const unsigned short *Bh, *Bl;
    if (sec == 0) { int sl = (t - 1) & 1; Bh = H0h + (size_t)sl * SLAB; Bl = H0l + (size_t)sl * SLAB; }
    else if (sec == 1) { int sl = t & 1; Bh = H0h + (size_t)sl * SLAB; Bl = H0l + (size_t)sl * SLAB; }
    else { int sl = (t - 1) & 1; Bh = H1h + (size_t)sl * SLAB; Bl = H1l + (size_t)sl * SLAB; }

    const unsigned short* Ab = pk + ((size_t)(sec * 32 + p) * 16) * 4096;
    const int brow = b0 + bcol * 16 + l15;
    const unsigned short* bhp = Bh + (size_t)brow * 512 + kk * 256 + l4 * 8;
    const unsigned short* blp = Bl + (size_t)brow * 512 + kk * 256 + l4 * 8;

    f32x4 cR = {0, 0, 0, 0}, cZ = cR, cN = cR;
    uint4 rg0, rg1, rg2, rg3;
    {
        const uint4* g0p = (const uint4*)Ab + (size_t)(kk * 8) * 512 + lt;
        rg0 = g0p[0]; rg1 = g0p[128]; rg2 = g0p[256]; rg3 = g0p[384];
        uint4* lp = (uint4*)lds + (kk * 2 + 0) * 512 + lt;
        lp[0] = rg0; lp[128] = rg1; lp[256] = rg2; lp[384] = rg3;
    }
    __syncthreads();
#pragma unroll
    for (int i = 0; i < 8; ++i) {
        const int d = i & 1;
        if (i < 7) {
            const uint4* gn = (const uint4*)Ab + (size_t)(kk * 8 + i + 1) * 512 + lt;
            rg0 = gn[0]; rg1 = gn[128]; rg2 = gn[256]; rg3 = gn[384];
        }
        const unsigned short* tb = lds + (kk * 2 + d) * 4096;
        bf16x8 aRh = *(const bf16x8*)(tb + (l15) * 40 + l4 * 8);
        bf16x8 aRl = *(const bf16x8*)(tb + 1920 + (l15) * 40 + l4 * 8);
        bf16x8 aZh = *(const bf16x8*)(tb + (16 + l15) * 40 + l4 * 8);
        bf16x8 aZl = *(const bf16x8*)(tb + 1920 + (16 + l15) * 40 + l4 * 8);
        bf16x8 aNh = *(const bf16x8*)(tb + (32 + l15) * 40 + l4 * 8);
        bf16x8 aNl = *(const bf16x8*)(tb + 1920 + (32 + l15) * 40 + l4 * 8);
        bf16x8 bh = *(const bf16x8*)(bhp + i * 32);
        bf16x8 bl = *(const bf16x8*)(blp + i * 32);
        cR = __builtin_amdgcn_mfma_f32_16x16x32_bf16(aRh, bh, cR, 0, 0, 0);
        cR = __builtin_amdgcn_mfma_f32_16x16x32_bf16(aRh, bl, cR, 0, 0, 0);
        cR = __builtin_amdgcn_mfma_f32_16x16x32_bf16(aRl, bh, cR, 0, 0, 0);
        cZ = __builtin_amdgcn_mfma_f32_16x16x32_bf16(aZh, bh, cZ, 0, 0, 0);
        cZ = __builtin_amdgcn_mfma_f32_16x16x32_bf16(aZh, bl, cZ, 0, 0, 0);
        cZ = __builtin_amdgcn_mfma_f32_16x16x32_bf16(aZl, bh, cZ, 0, 0, 0);
        cN = __builtin_amdgcn_mfma_f32_16x16x32_bf16(aNh, bh, cN, 0, 0, 0);
        cN = __builtin_amdgcn_mfma_f32_16x16x32_bf16(aNh, bl, cN, 0, 0, 0);
        cN = __builtin_amdgcn_mfma_f32_16x16x32_bf16(aNl, bh, cN, 0, 0, 0);
        if (i < 7) {
            uint4* lp = (uint4*)lds + (kk * 2 + (d ^ 1)) * 512 + lt;
            lp[0] = rg0; lp[128] = rg1; lp[256] = rg2; lp[384] = rg3;
        }
        __syncthreads();
    }
    // cross-k-group reduce (reuse lds)
    float* red = (float*)lds;
    if (kk == 1) {
        int o = (bcol * 64 + lane) * 12;
        *(f32x4*)(red + o) = cR; *(f32x4*)(red + o + 4) = cZ; *(f32x4*)(red + o + 8) = cN;
    }
    __syncthreads();
    if (kk == 0) {
        int o = (bcol * 64 + lane) * 12;
        f32x4 u;
        u = *(f32x4*)(red + o);     cR += u;
        u = *(f32x4*)(red + o + 4); cZ += u;
        u = *(f32x4*)(red + o + 8); cN += u;
        const int b = b0 + bcol * 16 + l15;
        if (sec == 1) {
            float* xo = xi1 + (size_t)(t & 1) * XSLAB;
#pragma unroll
            for (int q = 0; q < 4; ++q) {
                int jrow = p * 16 + l4 * 4 + q;
                xo[(size_t)jrow * 256 + b]          = cR[q] + bih1[jrow];
                xo[(size_t)(512 + jrow) * 256 + b]  = cZ[q] + bih1[512 + jrow];
                xo[(size_t)(1024 + jrow) * 256 + b] = cN[q] + bih1[1024 + jrow];
            }
        } else {
            const float *xi, *bhh, *hpv;
            float* hnew;
            if (sec == 0) {
                xi = xi0 + (size_t)(t & (CH - 1)) * XSLAB;
                bhh = bhh0;
                hpv = h0f + (size_t)((t - 1) & 1) * SLAB;
                hnew = h0f + (size_t)(t & 1) * SLAB;
            } else {
                xi = xi1 + (size_t)(t & 1) * XSLAB;
                bhh = bhh1;
                hpv = h1f + (size_t)((t - 1) & 1) * SLAB;
                hnew = h1f + (size_t)(t & 1) * SLAB;
            }
#pragma unroll
            for (int q = 0; q < 4; ++q) {
                int jl = l4 * 4 + q;
                int jrow = p * 16 + jl;
                float xr = xi[(size_t)jrow * 256 + b];
                float xz = xi[(size_t)(512 + jrow) * 256 + b];
                float xn = xi[(size_t)(1024 + jrow) * 256 + b];
                float hp = hpv[(size_t)jrow * 256 + b];
                float rr = sigm(xr + cR[q] + bhh[jrow]);
                float zz = sigm(xz + cZ[q] + bhh[512 + jrow]);
                float nn = tanhf(xn + rr * (cN[q] + bhh[1024 + jrow]));
                float hv = (1.f - zz) * nn + zz * hp;
                hnew[(size_t)jrow * 256 + b] = hv;
                hs[jl][bcol * 16 + l15] = hv;
            }
        }
    }
    if (sec != 1) {
        __syncthreads();
        if (tid < 128) {
            int blocal = tid >> 2, j4 = (tid & 3) * 4;
            unsigned short hq[4], lq[4];
#pragma unroll
            for (int i2 = 0; i2 < 4; ++i2) {
                float v = hs[j4 + i2][blocal];
                unsigned short hh = bf16_rne(v);
                hq[i2] = hh; lq[i2] = bf16_rne(v - bf16_tof(hh));
            }
            unsigned short *Hh, *Hl;
            if (sec == 0) { Hh = H0h + (size_t)(t & 1) * SLAB; Hl = H0l + (size_t)(t & 1) * SLAB; }
            else          { Hh = H1h + (size_t)(t & 1) * SLAB; Hl = H1l + (size_t)(t & 1) * SLAB; }
            size_t o = (size_t)(b0 + blocal) * 512 + p * 16 + j4;
            *(ushort4*)(Hh + o) = *(ushort4*)hq;
            *(ushort4*)(Hl + o) = *(ushort4*)lq;
        }
    }
}

// ---- tail -------------------------------------------------------------

__global__ __launch_bounds__(256) void hT_to_h(
    const float* __restrict__ hT, float* __restrict__ h) {
    __shared__ float tb[64][65];
    const int tid = threadIdx.x;
    const int k0 = blockIdx.x * 64, b0 = blockIdx.y * 64;
#pragma unroll
    for (int i = 0; i < 4; ++i) {
        int r = (tid >> 4) + 16 * i;
        int c = (tid & 15) * 4;
        float4 v = *(const float4*)(hT + (size_t)(k0 + r) * 256 + b0 + c);
        tb[c + 0][r] = v.x; tb[c + 1][r] = v.y; tb[c + 2][r] = v.z; tb[c + 3][r] = v.w;
    }
    __syncthreads();
#pragma unroll
    for (int i = 0; i < 4; ++i) {
        int r = (tid >> 4) + 16 * i;
        int c = (tid & 15) * 4;
        float4 v;
        v.x = tb[r][c]; v.y = tb[r][c + 1]; v.z = tb[r][c + 2]; v.w = tb[r][c + 3];
        *(float4*)(h + (size_t)(b0 + r) * 512 + k0 + c) = v;
    }
}

__device__ __forceinline__ float blockReduceSum(float v, float* tmp) {
    __syncthreads();
#pragma unroll
    for (int o = 32; o; o >>= 1) v += __shfl_down(v, o);
    if ((threadIdx.x & 63) == 0) tmp[threadIdx.x >> 6] = v;
    __syncthreads();
    if (threadIdx.x == 0) tmp[4] = tmp[0] + tmp[1] + tmp[2] + tmp[3];
    __syncthreads();
    return tmp[4];
}

__device__ __forceinline__ float blockReduceMax(float v, float* tmp) {
    __syncthreads();
#pragma unroll
    for (int o = 32; o; o >>= 1) v = fmaxf(v, __shfl_down(v, o));
    if ((threadIdx.x & 63) == 0) tmp[threadIdx.x >> 6] = v;
    __syncthreads();
    if (threadIdx.x == 0) tmp[4] = fmaxf(fmaxf(tmp[0], tmp[1]), fmaxf(tmp[2], tmp[3]));
    __syncthreads();
    return tmp[4];
}

__global__ __launch_bounds__(256) void head_kernel(
    const float* __restrict__ h1, const float* __restrict__ fcw,
    const float* __restrict__ fcb, float* __restrict__ out) {
    __shared__ __align__(16) float hrow[512];
    __shared__ float wv[512];
    __shared__ float ov[512];
    __shared__ float tmp[8];
    const int b = blockIdx.x, tid = threadIdx.x;
    hrow[tid]       = h1[(size_t)b * 512 + tid];
    hrow[tid + 256] = h1[(size_t)b * 512 + 256 + tid];
    __syncthreads();

    float s[2];
#pragma unroll
    for (int q = 0; q < 2; ++q) {
        int n = tid + q * 256;
        const float* wr = fcw + (size_t)n * 512;
        float acc = 0.f;
        for (int k = 0; k < 512; k += 4) {
            float4 wq = *(const float4*)(wr + k);
            acc += wq.x * hrow[k] + wq.y * hrow[k + 1] + wq.z * hrow[k + 2] + wq.w * hrow[k + 3];
        }
        float l = acc + fcb[n];
        s[q] = l / (1.f + expf(-l));
    }

    float mx = blockReduceMax(fmaxf(s[0], s[1]), tmp);
    float e0 = expf(s[0] - mx), e1 = expf(s[1] - mx);
    float sum = blockReduceSum(e0 + e1, tmp);
    float w0 = e0 / sum, w1 = e1 / sum;

    ov[tid] = w0;       ov[tid + 256] = w1;
    wv[tid]       = fminf(fmaxf(w0, 0.f), 0.1f);
    wv[tid + 256] = fminf(fmaxf(w1, 0.f), 0.1f);
    __syncthreads();

    for (int it = 0; it < 32; ++it) {
        float wc0 = wv[tid], wc1 = wv[tid + 256];
        float o0 = ov[tid], o1 = ov[tid + 256];
        float leftover = blockReduceSum((o0 - wc0) + (o1 - wc1), tmp);
        float n0 = (wc0 != 0.1f) ? wc0 : 0.f;
        float n1 = (wc1 != 0.1f) ? wc1 : 0.f;
        float denom = blockReduceSum(n0 + n1, tmp);
        float w20 = wc0 + leftover * n0 / denom;
        float w21 = wc1 + leftover * n1 / denom;
        float fl = ((w20 > 0.1f) || (w21 > 0.1f)) ? 1.f : 0.f;
        bool again = blockReduceSum(fl, tmp) > 0.f;
        __syncthreads();
        ov[tid] = w20; ov[tid + 256] = w21;
        wv[tid]       = again ? fminf(fmaxf(w20, 0.f), 0.1f) : w20;
        wv[tid + 256] = again ? fminf(fmaxf(w21, 0.f), 0.1f) : w21;
        __syncthreads();
        if (!again) break;
    }

    out[(size_t)b * 512 + tid]       = wv[tid];
    out[(size_t)b * 512 + 256 + tid] = wv[tid + 256];
}

extern "C" void kernel_launch(void* const* d_in, const int* in_sizes, int n_in,
                              void* d_out, int out_size, void* d_ws, size_t ws_size,
                              hipStream_t stream) {
    const float* x    = (const float*)d_in[0];
    const float* Wih0 = (const float*)d_in[1];
    const float* Whh0 = (const float*)d_in[2];
    const float* bih0 = (const float*)d_in[3];
    const float* bhh0 = (const float*)d_in[4];
    const float* Wih1 = (const float*)d_in[5];
    const float* Whh1 = (const float*)d_in[6];
    const float* bih1 = (const float*)d_in[7];
    const float* bhh1 = (const float*)d_in[8];
    const float* fcw  = (const float*)d_in[9];
    const float* fcb  = (const float*)d_in[10];
    float* out = (float*)d_out;

    const size_t WHALF = (size_t)G3 * HH;            // 786432
    unsigned short* W0h = (unsigned short*)d_ws;
    unsigned short* W0l = W0h + WHALF;
    unsigned short* pk  = W0l + WHALF;               // 1536*4096 ushorts
    float* xi0 = (float*)(pk + (size_t)1536 * 4096); // [CH][XSLAB]
    float* xi1 = xi0 + (size_t)CH * XSLAB;           // [2][XSLAB]
    float* h0f = xi1 + 2 * (size_t)XSLAB;            // [2][SLAB]
    float* h1f = h0f + 2 * (size_t)SLAB;             // [2][SLAB]
    float* h1n = h1f + 2 * (size_t)SLAB;             // [SLAB]
    unsigned short* H0h = (unsigned short*)(h1n + SLAB);  // [2][SLAB] each
    unsigned short* H0l = H0h + 2 * (size_t)SLAB;
    unsigned short* H1h = H0l + 2 * (size_t)SLAB;
    unsigned short* H1l = H1h + 2 * (size_t)SLAB;

    convert_split<<<(G3 * HH) / 1024, 256, 0, stream>>>(Wih0, W0h, W0l, G3 * HH);
    pack_rec<<<1536, 128, 0, stream>>>(Whh0, Wih1, Whh1, pk);
    zero_kernel<<<SLAB / 256, 256, 0, stream>>>(h0f + SLAB, SLAB);
    zero_kernel<<<SLAB / 256, 256, 0, stream>>>(h1f + SLAB, SLAB);
    zero_kernel<<<(SLAB / 2) / 256, 256, 0, stream>>>((float*)(H0h + SLAB), SLAB / 2);
    zero_kernel<<<(SLAB / 2) / 256, 256, 0, stream>>>((float*)(H0l + SLAB), SLAB / 2);
    zero_kernel<<<(SLAB / 2) / 256, 256, 0, stream>>>((float*)(H1h + SLAB), SLAB / 2);
    zero_kernel<<<(SLAB / 2) / 256, 256, 0, stream>>>((float*)(H1l + SLAB), SLAB / 2);

    for (int c = 0; c < TT / CH; ++c) {
        xi_mfma_x<<<dim3(CH * 2, 12), 256, 0, stream>>>(W0h, W0l, x, c * CH, bih0, xi0);
        for (int tl = 0; tl < CH; ++tl) {
            int s = c * CH + tl;
            step_mfma<<<768, 256, 0, stream>>>(s, pk, xi0, xi1, bih1, bhh0, bhh1,
                                               h0f, h1f, H0h, H0l, H1h, H1l);
        }
    }
    step_mfma<<<768, 256, 0, stream>>>(128, pk, xi0, xi1, bih1, bhh0, bhh1,
                                       h0f, h1f, H0h, H0l, H1h, H1l);
    step_mfma<<<768, 256, 0, stream>>>(129, pk, xi0, xi1, bih1, bhh0, bhh1,
                                       h0f, h1f, H0h, H0l, H1h, H1l);

    hT_to_h<<<dim3(8, 4), 256, 0, stream>>>(h1f + SLAB, h1n);
    head_kernel<<<BB, 256, 0, stream>>>(h1n, fcw, fcb, out);
}